// Round 11
// baseline (113.231 us; speedup 1.0000x reference)
//
#include <hip/hip_runtime.h>
#include <stdint.h>
#include <stddef.h>

// MambaMesh random-walk + gather-recenter.  R11: walk-per-LANE SIMT.
// PRNG (bit-exact vs JAX partitionable Threefry, verified R1-R10, absmax 0.0):
//   split(key,n)[j]        = threefry2x32(key; 0, j)   (both output words)
//   random_bits(key,32,()) = xor-fold of threefry2x32(key; 0, 0)
// R9/R10 lessons: wave-per-walk pays ~11 DS + ~75 VALU per step PER WAVE
// (x16 waves/CU -> LDS-pipe bound ~1020 cyc/step); VMEM rows re-create the
// pointer-chase (~1520 cyc/step). R11: 16 walks ride lanes 0-15 of ONE wave
// -> per-step cost paid once for 16 walks. Three dispatches:
//   K1 codes_kernel: chains+randint trees -> u8 pick-codes in ws (R5-verified)
//   K2 walk_kernel : 256 blocks, stage nb(u32+u16,120KB)+16 bitmaps(40KB)+
//                    codes+seq(u16) in LDS (163,776B); waves1-3 exit; wave0
//                    lanes0-15 SIMT-walk; dump seq -> ws
//   K3 gather_kernel: out[w,t,:] = xyz[seq[w,t]] - xyz[center]
// Rare paths recompute keys live from k0 (no keys in ws). Fallbacks: device
// (weird shapes) = per-lane linear-scan walk via ws vis-list; host (small
// ws) = fused hist kernel (verified R5/R8 logic).

namespace {

__device__ __forceinline__ uint32_t rotl32(uint32_t x, int r) {
  return (x << r) | (x >> (32 - r));
}

// Threefry-2x32, 20 rounds — exactly JAX's threefry2x32_p.
__device__ __forceinline__ void tf2x32(uint32_t ka, uint32_t kb,
                                       uint32_t x0, uint32_t x1,
                                       uint32_t& o0, uint32_t& o1) {
  const uint32_t kc = ka ^ kb ^ 0x1BD11BDAu;
  x0 += ka; x1 += kb;
#define TF_R4(r0, r1, r2, r3)                          \
  x0 += x1; x1 = rotl32(x1, r0); x1 ^= x0;             \
  x0 += x1; x1 = rotl32(x1, r1); x1 ^= x0;             \
  x0 += x1; x1 = rotl32(x1, r2); x1 ^= x0;             \
  x0 += x1; x1 = rotl32(x1, r3); x1 ^= x0;
  TF_R4(13, 15, 26, 6)  x0 += kb; x1 += kc + 1u;
  TF_R4(17, 29, 16, 24) x0 += kc; x1 += ka + 2u;
  TF_R4(13, 15, 26, 6)  x0 += ka; x1 += kb + 3u;
  TF_R4(17, 29, 16, 24) x0 += kb; x1 += kc + 4u;
  TF_R4(13, 15, 26, 6)  x0 += kc; x1 += ka + 5u;
#undef TF_R4
  o0 = x0; o1 = x1;
}

__device__ __forceinline__ void randbits(uint32_t ka, uint32_t kb,
                                         uint32_t& hi, uint32_t& lo) {
  uint32_t s0a, s0b, s1a, s1b, h0, h1;
  tf2x32(ka, kb, 0u, 0u, s0a, s0b);
  tf2x32(ka, kb, 0u, 1u, s1a, s1b);
  tf2x32(s0a, s0b, 0u, 0u, h0, h1);
  hi = h0 ^ h1;
  tf2x32(s1a, s1b, 0u, 0u, h0, h1);
  lo = h0 ^ h1;
}

__device__ __forceinline__ uint32_t r_generic(uint32_t hi, uint32_t lo,
                                              uint32_t span) {
  uint32_t mult = 65536u % span;
  mult = (mult * mult) % span;
  return ((hi % span) * mult + (lo % span)) % span;
}

// pick code: r3 (span=3 result) in bits 0..1, r2 (span=2 result) in bit 2.
__device__ __forceinline__ uint32_t pick_code(uint32_t hi, uint32_t lo) {
  return ((hi % 3u + lo % 3u) % 3u) | ((lo & 1u) << 2);
}

// k_idx: carry chain recomputed from k0 (RARE paths only).
__device__ __noinline__ void live_key(int w, int idx, uint32_t& ka,
                                      uint32_t& kb) {
  tf2x32(0u, 42u, 0u, (uint32_t)w, ka, kb);
  for (int c = 0; c < idx; ++c) tf2x32(ka, kb, 0u, 0u, ka, kb);
}

constexpr int CH = 64;       // cached code steps (covers seq_len 63)
constexpr int WPB = 16;      // walks per block
constexpr int BMW = 626;     // bitmap words per walk
constexpr int NMAX = BMW * 32;  // 20032 rows max for fast path
constexpr int SEQS = 66;     // seqL stride (u16 entries)
constexpr int VCAP = 96;     // fallback visited-list capacity

// ---------------- K1: per-step pick codes -> ws ---------------------------
__global__ __launch_bounds__(1024) void codes_kernel(
    uint8_t* __restrict__ codes_g, int num_walks) {
  __shared__ uint2 keysL[WPB][CH + 1];
  const int tid = threadIdx.x, wv = tid >> 6, lane = tid & 63;
  const int w0 = blockIdx.x * WPB, w = w0 + wv;
  if (wv == 0 && lane < WPB && (w0 + lane) < num_walks) {
    uint32_t ka, kb;
    tf2x32(0u, 42u, 0u, (uint32_t)(w0 + lane), ka, kb);  // k_0
    keysL[lane][0] = make_uint2(ka, kb);
#pragma clang loop unroll(disable)
    for (int c = 1; c < CH; ++c) {
      tf2x32(ka, kb, 0u, 0u, ka, kb);
      keysL[lane][c] = make_uint2(ka, kb);
    }
  }
  __syncthreads();
  if (w >= num_walks) return;
  const uint2 kc = keysL[wv][lane];
  uint32_t k1a, k1b, hi, lo;
  tf2x32(kc.x, kc.y, 0u, 1u, k1a, k1b);  // k1 = split(k,4)[1]
  randbits(k1a, k1b, hi, lo);
  codes_g[(size_t)w * CH + lane] = (uint8_t)pick_code(hi, lo);
}

// ---------------- K2: the walk (walk-per-lane SIMT) -----------------------
__global__ __launch_bounds__(256) void walk_kernel(
    const int* __restrict__ nbrs, const int* __restrict__ centers,
    const int* __restrict__ n_faces_p, const int* __restrict__ seq_len_p,
    const uint8_t* __restrict__ codes_g, uint32_t* __restrict__ seq_g,
    uint32_t* __restrict__ vis_g, int s0, int num_walks, int Lp1) {
  __shared__ uint32_t nb01L[NMAX];        // n0 | n1<<16        80,128 B
  __shared__ uint16_t nb2L[NMAX];         // n2                 40,064 B
  __shared__ uint32_t visL[WPB * BMW];    // bitmaps            40,064 B
  __shared__ uint16_t seqL[WPB * SEQS];   // seq                 2,112 B
  __shared__ uint8_t  codesL[WPB * CH];   // pick codes          1,024 B

  const int tid = threadIdx.x, lane = tid & 63;
  const int w0 = blockIdx.x * WPB;
  if (w0 >= num_walks) return;
  const int N = *n_faces_p, L = *seq_len_p;
  const int B = s0 / (3 * N), G = num_walks / B;
  const int wlast = (w0 + WPB - 1 < num_walks) ? w0 + WPB - 1 : num_walks - 1;
  const bool fast = (N <= NMAX) && (Lp1 <= CH) && (L + 1 < SEQS) &&
                    ((w0 / G) == (wlast / G));

  if (fast) {
    const int* __restrict__ nbs = nbrs + (size_t)(w0 / G) * N * 3;
    for (int r = tid; r < N; r += 256) {
      const int3 v = *reinterpret_cast<const int3*>(nbs + 3 * (size_t)r);
      nb01L[r] = (uint32_t)v.x | ((uint32_t)v.y << 16);
      nb2L[r] = (uint16_t)v.z;
    }
    for (int j = tid; j < WPB * BMW; j += 256) visL[j] = 0u;
    const int wcnt = wlast - w0 + 1;                    // valid walks
    const uint32_t* src = reinterpret_cast<const uint32_t*>(
        codes_g + (size_t)w0 * CH);
    for (int j = tid; j < (wcnt * CH) / 4; j += 256)
      reinterpret_cast<uint32_t*>(codesL)[j] = src[j];
  }
  __syncthreads();
  if (tid >= 64) return;   // waves 1-3 done (no further barriers)

  const int wl = lane;            // walk-in-block (lanes 0..15 active)
  const int wg = w0 + wl;
  const bool alive = (wl < WPB) && (wg < num_walks);

  if (fast) {
    int f0 = 0, n0 = 0, n1 = 0, n2 = 0, i = 1, bs = 1, cstep = 0;
    if (alive) {
      f0 = centers[wg];
      seqL[wl * SEQS + 0] = (uint16_t)f0;
      visL[wl * BMW + ((unsigned)f0 >> 5)] = 1u << (f0 & 31);
      const uint32_t p = nb01L[f0];
      n0 = (int)(p & 0xffffu); n1 = (int)(p >> 16); n2 = (int)nb2L[f0];
    }
    for (;;) {
      const bool go = alive && (i <= L);
      if (!__ballot(go)) break;
      if (go) {
        const int idx = cstep; ++cstep;
        // one LDS round for everything this step needs (per-lane scattered)
        const uint32_t wa = visL[wl * BMW + ((unsigned)n0 >> 5)];
        const uint32_t wb = visL[wl * BMW + ((unsigned)n1 >> 5)];
        const uint32_t wc = visL[wl * BMW + ((unsigned)n2 >> 5)];
        const uint32_t pA = nb01L[n0]; const uint32_t a2 = nb2L[n0];
        const uint32_t pB = nb01L[n1]; const uint32_t b2 = nb2L[n1];
        const uint32_t pC = nb01L[n2]; const uint32_t c2 = nb2L[n2];
        const uint32_t u0 = ((wa >> (n0 & 31)) & 1u) ^ 1u;
        const uint32_t u1 = ((wb >> (n1 & 31)) & 1u) ^ 1u;
        const uint32_t u2 = ((wc >> (n2 & 31)) & 1u) ^ 1u;
        const uint32_t cnt = u0 + u1 + u2;

        int to_add, sel;
        if (__builtin_expect(cnt == 0, 0)) {
          // ---- rare backtrack (per-lane, live hashing, bit-exact) ----
          sel = -1;
          uint32_t kia, kib;
          live_key(wg, idx, kia, kib);
          uint32_t kka, kkb;
          tf2x32(kia, kib, 0u, 2u, kka, kkb);  // k2
          bool found = false;
          int ta = 0, bsc = bs;
          while (!found && i > bsc) {
            uint32_t ca, cb, kpa, kpb;
            tf2x32(kka, kkb, 0u, 0u, ca, cb);
            tf2x32(kka, kkb, 0u, 1u, kpa, kpb);
            const int back = (int)seqL[wl * SEQS + (i - bsc - 1)];
            const uint32_t pm = nb01L[back];
            const int m0 = (int)(pm & 0xffffu), m1 = (int)(pm >> 16);
            const int m2 = (int)nb2L[back];
            const uint32_t e0 =
                ((visL[wl * BMW + (m0 >> 5)] >> (m0 & 31)) & 1u) ^ 1u;
            const uint32_t e1 =
                ((visL[wl * BMW + (m1 >> 5)] >> (m1 & 31)) & 1u) ^ 1u;
            const uint32_t e2 =
                ((visL[wl * BMW + (m2 >> 5)] >> (m2 & 31)) & 1u) ^ 1u;
            const uint32_t bc = e0 + e1 + e2;
            if (bc > 0) {
              uint32_t bhi, blo;
              randbits(kpa, kpb, bhi, blo);
              const uint32_t bcode = pick_code(bhi, blo);
              const uint32_t r3 = bcode & 3u, r2 = (bcode >> 2) & 1u;
              const uint32_t t2v = (bc == 3 ? r3 : (bc == 2 ? r2 : 0)) + 1;
              ta = (e0 == t2v) ? m0 : ((e0 + e1 == t2v) ? m1 : m2);
              found = true;
            } else {
              bsc += 2;
            }
            kka = ca; kkb = cb;
          }
          if (found) {
            const int i_new = i - bsc;
            for (int a = i_new; a < i; ++a)
              seqL[wl * SEQS + a] = (uint16_t)ta;   // ref's seq-splat
            to_add = ta; bs = bsc; i = i_new;
          } else {
            uint32_t k3a, k3b, rh, rl;
            tf2x32(kia, kib, 0u, 3u, k3a, k3b);  // k3
            randbits(k3a, k3b, rh, rl);
            to_add = (int)r_generic(rh, rl, (uint32_t)N);
            bs = 1;
          }
        } else {
          // ---- common path ----
          uint32_t code;
          if (__builtin_expect(idx >= CH, 0)) {  // beyond cached steps
            uint32_t ia, ib, k1a, k1b, h2, l2;
            live_key(wg, idx, ia, ib);
            tf2x32(ia, ib, 0u, 1u, k1a, k1b);
            randbits(k1a, k1b, h2, l2);
            code = pick_code(h2, l2);
          } else {
            code = codesL[(wl << 6) | idx];
          }
          const uint32_t r3 = code & 3u, r2 = (code >> 2) & 1u;
          const uint32_t target = (cnt == 3 ? r3 : (cnt == 2 ? r2 : 0)) + 1;
          sel = (u0 == target) ? 0 : ((u0 + u1 == target) ? 1 : 2);
          to_add = (sel == 0) ? n0 : ((sel == 1) ? n1 : n2);
          bs = 1;
        }
        // ---- common tail: mark visited, append seq, select next row ----
        const unsigned word = wl * BMW + ((unsigned)to_add >> 5);
        visL[word] = visL[word] | (1u << (to_add & 31));
        seqL[wl * SEQS + i] = (uint16_t)to_add;
        ++i;
        if (sel == 0)      { n0 = (int)(pA & 0xffffu); n1 = (int)(pA >> 16); n2 = (int)a2; }
        else if (sel == 1) { n0 = (int)(pB & 0xffffu); n1 = (int)(pB >> 16); n2 = (int)b2; }
        else if (sel == 2) { n0 = (int)(pC & 0xffffu); n1 = (int)(pC >> 16); n2 = (int)c2; }
        else {
          const uint32_t p = nb01L[to_add];
          n0 = (int)(p & 0xffffu); n1 = (int)(p >> 16); n2 = (int)nb2L[to_add];
        }
      }
    }
    // Dump seq -> ws (all 64 lanes, coalesced per walk).
    for (int k = 0; k < WPB; ++k) {
      const int wgk = w0 + k;
      if (wgk < num_walks && lane < Lp1)
        seq_g[(size_t)wgk * Lp1 + lane] = (uint32_t)seqL[k * SEQS + lane];
    }
  } else {
    // ---- device fallback: per-lane walk, linear-scan visited (correct,
    //      slow; only for shapes the fast path can't host) ----
    if (!alive) return;
    uint32_t* __restrict__ vlist = vis_g + (size_t)wg * VCAP;
    int nvis = 0;
    const int bbl = wg / G;
    const int* __restrict__ nbl = nbrs + (size_t)bbl * N * 3;
    const int f0 = centers[wg];
    vlist[nvis++] = (uint32_t)f0;
    seq_g[(size_t)wg * Lp1 + 0] = (uint32_t)f0;
    int3 row = *reinterpret_cast<const int3*>(nbl + 3 * (size_t)f0);
    int i = 1, bs = 1, cstep = 0;
    auto unv = [&](int node) -> uint32_t {
      for (int k = 0; k < nvis; ++k)
        if ((int)vlist[k] == node) return 0u;
      return 1u;
    };
    while (i <= L) {
      const int idx = cstep; ++cstep;
      const uint32_t u0 = unv(row.x), u1 = unv(row.y), u2 = unv(row.z);
      const uint32_t cnt = u0 + u1 + u2;
      int to_add;
      if (cnt == 0) {
        uint32_t kia, kib;
        live_key(wg, idx, kia, kib);
        uint32_t kka, kkb;
        tf2x32(kia, kib, 0u, 2u, kka, kkb);
        bool found = false;
        int ta = 0, bsc = bs;
        while (!found && i > bsc) {
          uint32_t ca, cb, kpa, kpb;
          tf2x32(kka, kkb, 0u, 0u, ca, cb);
          tf2x32(kka, kkb, 0u, 1u, kpa, kpb);
          const int back = (int)seq_g[(size_t)wg * Lp1 + (i - bsc - 1)];
          const int3 br = *reinterpret_cast<const int3*>(nbl + 3 * (size_t)back);
          const uint32_t e0 = unv(br.x), e1 = unv(br.y), e2 = unv(br.z);
          const uint32_t bc = e0 + e1 + e2;
          if (bc > 0) {
            uint32_t bhi, blo;
            randbits(kpa, kpb, bhi, blo);
            const uint32_t bcode = pick_code(bhi, blo);
            const uint32_t r3 = bcode & 3u, r2 = (bcode >> 2) & 1u;
            const uint32_t t2v = (bc == 3 ? r3 : (bc == 2 ? r2 : 0)) + 1;
            ta = (e0 == t2v) ? br.x : ((e0 + e1 == t2v) ? br.y : br.z);
            found = true;
          } else {
            bsc += 2;
          }
          kka = ca; kkb = cb;
        }
        if (found) {
          const int i_new = i - bsc;
          for (int a = i_new; a < i; ++a)
            seq_g[(size_t)wg * Lp1 + a] = (uint32_t)ta;
          to_add = ta; bs = bsc; i = i_new;
        } else {
          uint32_t k3a, k3b, rh, rl;
          tf2x32(kia, kib, 0u, 3u, k3a, k3b);
          randbits(k3a, k3b, rh, rl);
          to_add = (int)r_generic(rh, rl, (uint32_t)N);
          bs = 1;
        }
      } else {
        uint32_t code;
        if (idx >= CH) {
          uint32_t ia, ib, k1a, k1b, h2, l2;
          live_key(wg, idx, ia, ib);
          tf2x32(ia, ib, 0u, 1u, k1a, k1b);
          randbits(k1a, k1b, h2, l2);
          code = pick_code(h2, l2);
        } else {
          code = codes_g[(size_t)wg * CH + idx];
        }
        const uint32_t r3 = code & 3u, r2 = (code >> 2) & 1u;
        const uint32_t target = (cnt == 3 ? r3 : (cnt == 2 ? r2 : 0)) + 1;
        to_add = (u0 == target) ? row.x
               : ((u0 + u1 == target) ? row.y : row.z);
        bs = 1;
      }
      if (nvis < VCAP) vlist[nvis++] = (uint32_t)to_add;
      seq_g[(size_t)wg * Lp1 + i] = (uint32_t)to_add;
      ++i;
      row = *reinterpret_cast<const int3*>(nbl + 3 * (size_t)to_add);
    }
  }
}

// ---------------- K3: gather + recenter -----------------------------------
__global__ __launch_bounds__(256) void gather_kernel(
    const float* __restrict__ xyz, const int* __restrict__ centers,
    const int* __restrict__ n_faces_p, const uint32_t* __restrict__ seq_g,
    float* __restrict__ out, int s0, int num_walks, int Lp1) {
  const int idx = blockIdx.x * 256 + threadIdx.x;
  if (idx >= num_walks * Lp1) return;
  const int w = idx / Lp1;
  const int N = *n_faces_p;
  const int B = s0 / (3 * N), G = num_walks / B, b = w / G;
  const float* __restrict__ xb = xyz + (size_t)b * N * 3;
  const int node = (int)seq_g[idx];
  const int c0 = centers[w];
  float3 v;
  v.x = xb[3 * (size_t)node + 0] - xb[3 * (size_t)c0 + 0];
  v.y = xb[3 * (size_t)node + 1] - xb[3 * (size_t)c0 + 1];
  v.z = xb[3 * (size_t)node + 2] - xb[3 * (size_t)c0 + 2];
  reinterpret_cast<float3*>(out)[idx] = v;
}

// ---------------- Host fallback: fused hist kernel (verified logic) -------
constexpr int KSTRIDE = 65;
__global__ __launch_bounds__(1024) void fused_kernel(
    const float* __restrict__ xyz, const int* __restrict__ nbrs,
    const int* __restrict__ centers, const int* __restrict__ n_faces_p,
    const int* __restrict__ seq_len_p, float* __restrict__ out,
    int s0, int num_walks, int Lp1) {
  __shared__ uint2 keysL[WPB * KSTRIDE];
  const int tid = threadIdx.x, wv = tid >> 6, lane = tid & 63;
  const int w0 = blockIdx.x * WPB;
  if (w0 >= num_walks) return;
  const int w = w0 + wv;
  const bool active = (w < num_walks);
  const int N = *n_faces_p, L = *seq_len_p;
  const int B = s0 / (3 * N), G = num_walks / B;
  const int bb = (active ? w : w0) / G;
  const int* __restrict__ nb   = nbrs + (size_t)bb * N * 3;
  const float* __restrict__ xb = xyz + (size_t)bb * N * 3;
  const int f0 = active ? centers[w] : 0;
  int3 row = active ? *reinterpret_cast<const int3*>(nb + 3 * (size_t)f0)
                    : make_int3(0, 0, 0);
  if (wv == 0 && lane < WPB && (w0 + lane) < num_walks) {
    uint32_t ka, kb;
    tf2x32(0u, 42u, 0u, (uint32_t)(w0 + lane), ka, kb);
    keysL[lane * KSTRIDE + 0] = make_uint2(ka, kb);
#pragma clang loop unroll(disable)
    for (int c2 = 1; c2 < CH; ++c2) {
      tf2x32(ka, kb, 0u, 0u, ka, kb);
      keysL[lane * KSTRIDE + c2] = make_uint2(ka, kb);
    }
  }
  __syncthreads();
  if (!active) return;
  const uint2 mykey = keysL[wv * KSTRIDE + lane];
  uint32_t mycode;
  {
    uint32_t k1a, k1b, hi, lo;
    tf2x32(mykey.x, mykey.y, 0u, 1u, k1a, k1b);
    randbits(k1a, k1b, hi, lo);
    mycode = pick_code(hi, lo);
  }
  uint32_t extka = 0, extkb = 0;
  int extc = -1;
  auto get_key = [&](int idx, uint32_t& ra, uint32_t& rb) {
    if (idx < CH) {
      ra = (uint32_t)__shfl((int)mykey.x, idx);
      rb = (uint32_t)__shfl((int)mykey.y, idx);
    } else {
      if (extc < 0) {
        extka = (uint32_t)__shfl((int)mykey.x, CH - 1);
        extkb = (uint32_t)__shfl((int)mykey.y, CH - 1);
        extc = CH - 1;
      }
      while (extc < idx) { tf2x32(extka, extkb, 0u, 0u, extka, extkb); ++extc; }
      ra = extka; rb = extkb;
    }
  };
  int hist = (lane == 0) ? f0 : -1, hist2 = -1;
  int seqr = (lane == 0) ? f0 : -1;
  int i = 1, bs = 1, c = 0;
  while (i <= L) {
    const int idx = c; ++c;
    const bool deep = (idx >= CH);
    const int n0 = row.x, n1 = row.y, n2 = row.z;
    int v0 = __any(hist == n0), v1 = __any(hist == n1), v2 = __any(hist == n2);
    if (deep) {
      v0 |= __any(hist2 == n0); v1 |= __any(hist2 == n1); v2 |= __any(hist2 == n2);
    }
    const int u0 = 1 - v0, u1 = 1 - v1, u2 = 1 - v2;
    const int cnt = u0 + u1 + u2;
    int to_add; bool hit = false; int bsf = bs;
    if (cnt > 0) {
      uint32_t code;
      if (deep) {
        uint32_t ia, ib, k1a, k1b, hi, lo;
        get_key(idx, ia, ib);
        tf2x32(ia, ib, 0u, 1u, k1a, k1b);
        randbits(k1a, k1b, hi, lo);
        code = pick_code(hi, lo);
      } else {
        code = (uint32_t)__builtin_amdgcn_readlane((int)mycode, idx);
      }
      const int r3 = (int)(code & 3u), r2 = (int)((code >> 2) & 1u);
      const int target = (cnt == 3 ? r3 : (cnt == 2 ? r2 : 0)) + 1;
      to_add = (u0 == target) ? n0 : ((u0 + u1 == target) ? n1 : n2);
    } else {
      uint32_t kia, kib;
      get_key(idx, kia, kib);
      uint32_t kka, kkb;
      tf2x32(kia, kib, 0u, 2u, kka, kkb);
      bool found = false; int ta = 0, bsc = bs;
      while (!found && i > bsc) {
        uint32_t ca, cb, kpa, kpb;
        tf2x32(kka, kkb, 0u, 0u, ca, cb);
        tf2x32(kka, kkb, 0u, 1u, kpa, kpb);
        const int back = __shfl(seqr, i - bsc - 1);
        const int3 br = *reinterpret_cast<const int3*>(nb + 3 * (size_t)back);
        int a0 = __any(hist == br.x), a1 = __any(hist == br.y), a2m = __any(hist == br.z);
        if (deep) {
          a0 |= __any(hist2 == br.x); a1 |= __any(hist2 == br.y); a2m |= __any(hist2 == br.z);
        }
        const int e0 = 1 - a0, e1 = 1 - a1, e2 = 1 - a2m;
        const int bc = e0 + e1 + e2;
        if (bc > 0) {
          uint32_t bhi, blo;
          randbits(kpa, kpb, bhi, blo);
          const uint32_t bcode = pick_code(bhi, blo);
          const int r3 = (int)(bcode & 3u), r2 = (int)((bcode >> 2) & 1u);
          const int t2v = (bc == 3 ? r3 : (bc == 2 ? r2 : 0)) + 1;
          ta = (e0 == t2v) ? br.x : ((e0 + e1 == t2v) ? br.y : br.z);
          found = true;
        } else bsc += 2;
        kka = ca; kkb = cb;
      }
      if (found) { to_add = ta; hit = true; bsf = bsc; }
      else {
        uint32_t k3a, k3b, rh, rl;
        tf2x32(kia, kib, 0u, 3u, k3a, k3b);
        randbits(k3a, k3b, rh, rl);
        to_add = (int)r_generic(rh, rl, (uint32_t)N);
      }
    }
    int i_new, up;
    if (hit) { i_new = i - bsf; bs = bsf; up = i - 1; }
    else     { i_new = i;       bs = 1;   up = i; }
    seqr = (lane >= i_new && lane <= up) ? to_add : seqr;
    const int slot = idx + 1;
    if (slot < CH)          hist  = (lane == slot)      ? to_add : hist;
    else if (slot < 2 * CH) hist2 = (lane == slot - CH) ? to_add : hist2;
    i = i_new + 1;
    row = *reinterpret_cast<const int3*>(nb + 3 * (size_t)to_add);
  }
  const float cx = xb[3 * (size_t)f0 + 0];
  const float cy = xb[3 * (size_t)f0 + 1];
  const float cz = xb[3 * (size_t)f0 + 2];
  if (lane < Lp1) {
    const int node = seqr;
    float3 v;
    v.x = xb[3 * (size_t)node + 0] - cx;
    v.y = xb[3 * (size_t)node + 1] - cy;
    v.z = xb[3 * (size_t)node + 2] - cz;
    *reinterpret_cast<float3*>(out + ((size_t)w * Lp1 + lane) * 3) = v;
  }
}

}  // namespace

extern "C" void kernel_launch(void* const* d_in, const int* in_sizes, int n_in,
                              void* d_out, int out_size, void* d_ws, size_t ws_size,
                              hipStream_t stream) {
  const float* xyz     = (const float*)d_in[0];
  const int*   nbrs    = (const int*)d_in[1];
  const int*   centers = (const int*)d_in[2];
  const int*   n_faces = (const int*)d_in[3];
  const int*   seq_len = (const int*)d_in[4];
  float* out = (float*)d_out;

  const int s0 = in_sizes[0];                  // B*N*3
  const int num_walks = in_sizes[2];           // B*G
  const int Lp1 = out_size / (3 * num_walks);  // seq_len+1

  const size_t codes_sz = (size_t)num_walks * CH;               // u8
  const size_t seq_off  = (codes_sz + 255) & ~(size_t)255;
  const size_t seq_sz   = (size_t)num_walks * Lp1 * 4;
  const size_t vis_off  = (seq_off + seq_sz + 255) & ~(size_t)255;
  const size_t need     = vis_off + (size_t)num_walks * VCAP * 4;

  const int blocks16 = (num_walks + WPB - 1) / WPB;
  if (ws_size >= need) {
    uint8_t*  codes_g = (uint8_t*)d_ws;
    uint32_t* seq_g   = (uint32_t*)((char*)d_ws + seq_off);
    uint32_t* vis_g   = (uint32_t*)((char*)d_ws + vis_off);
    codes_kernel<<<blocks16, 1024, 0, stream>>>(codes_g, num_walks);
    walk_kernel<<<blocks16, 256, 0, stream>>>(
        nbrs, centers, n_faces, seq_len, codes_g, seq_g, vis_g,
        s0, num_walks, Lp1);
    const int total = num_walks * Lp1;
    gather_kernel<<<(total + 255) / 256, 256, 0, stream>>>(
        xyz, centers, n_faces, seq_g, out, s0, num_walks, Lp1);
  } else {
    fused_kernel<<<blocks16, WPB * 64, 0, stream>>>(
        xyz, nbrs, centers, n_faces, seq_len, out, s0, num_walks, Lp1);
  }
}

// Round 12
// 103.832 us; speedup vs baseline: 1.0905x; 1.0905x over previous
//
#include <hip/hip_runtime.h>
#include <stdint.h>
#include <stddef.h>

// MambaMesh random-walk + gather-recenter.  R12: ws-free fused SIMT walk.
// PRNG (bit-exact vs JAX partitionable Threefry, verified R1-R11, absmax 0.0):
//   split(key,n)[j]        = threefry2x32(key; 0, j)   (both output words)
//   random_bits(key,32,()) = xor-fold of threefry2x32(key; 0, 0)
// R11 lesson: the walk-per-lane SIMT pipeline cut kernel time to ~17us, but
// d_ws use triggers a 268MB 0xAA re-poison fill (~40us) serialized into every
// timed replay (fills only appear in ws-using rounds R5/R11). R12 folds
// codes+walk+gather into ONE 256-thread kernel, zero d_ws:
//   A: wave0 lanes0-15 chains (keys -> bitmap scratch)  ||  threads 64-255
//      stage nb (u32 n0|n1 + u16 n2) into LDS
//   B: 256 thr x 4 randint trees -> codesL
//   C: zero bitmaps; wave0 runs the R11-verified SIMT walk (16 walks on
//      lanes 0-15); waves 1-3 wait at the final barrier
//   D: 256 thr gather out[w,t,:] = xyz[seq[t]] - xyz[center] from seqL
// LDS 163,392 B (<= 163,840). Companion any-shape fallback kernel (R10,
// verified) exits instantly when the fast shape holds.

namespace {

__device__ __forceinline__ uint32_t rotl32(uint32_t x, int r) {
  return (x << r) | (x >> (32 - r));
}

// Threefry-2x32, 20 rounds — exactly JAX's threefry2x32_p.
__device__ __forceinline__ void tf2x32(uint32_t ka, uint32_t kb,
                                       uint32_t x0, uint32_t x1,
                                       uint32_t& o0, uint32_t& o1) {
  const uint32_t kc = ka ^ kb ^ 0x1BD11BDAu;
  x0 += ka; x1 += kb;
#define TF_R4(r0, r1, r2, r3)                          \
  x0 += x1; x1 = rotl32(x1, r0); x1 ^= x0;             \
  x0 += x1; x1 = rotl32(x1, r1); x1 ^= x0;             \
  x0 += x1; x1 = rotl32(x1, r2); x1 ^= x0;             \
  x0 += x1; x1 = rotl32(x1, r3); x1 ^= x0;
  TF_R4(13, 15, 26, 6)  x0 += kb; x1 += kc + 1u;
  TF_R4(17, 29, 16, 24) x0 += kc; x1 += ka + 2u;
  TF_R4(13, 15, 26, 6)  x0 += ka; x1 += kb + 3u;
  TF_R4(17, 29, 16, 24) x0 += kb; x1 += kc + 4u;
  TF_R4(13, 15, 26, 6)  x0 += kc; x1 += ka + 5u;
#undef TF_R4
  o0 = x0; o1 = x1;
}

__device__ __forceinline__ void randbits(uint32_t ka, uint32_t kb,
                                         uint32_t& hi, uint32_t& lo) {
  uint32_t s0a, s0b, s1a, s1b, h0, h1;
  tf2x32(ka, kb, 0u, 0u, s0a, s0b);
  tf2x32(ka, kb, 0u, 1u, s1a, s1b);
  tf2x32(s0a, s0b, 0u, 0u, h0, h1);
  hi = h0 ^ h1;
  tf2x32(s1a, s1b, 0u, 0u, h0, h1);
  lo = h0 ^ h1;
}

__device__ __forceinline__ uint32_t r_generic(uint32_t hi, uint32_t lo,
                                              uint32_t span) {
  uint32_t mult = 65536u % span;
  mult = (mult * mult) % span;
  return ((hi % span) * mult + (lo % span)) % span;
}

// pick code: r3 (span=3 result) in bits 0..1, r2 (span=2 result) in bit 2.
__device__ __forceinline__ uint32_t pick_code(uint32_t hi, uint32_t lo) {
  return ((hi % 3u + lo % 3u) % 3u) | ((lo & 1u) << 2);
}

// k_idx recomputed from k0 — RARE paths only (bit-exact).
__device__ __noinline__ void live_key(int w, int idx, uint32_t& ka,
                                      uint32_t& kb) {
  tf2x32(0u, 42u, 0u, (uint32_t)w, ka, kb);
  for (int c = 0; c < idx; ++c) tf2x32(ka, kb, 0u, 0u, ka, kb);
}

constexpr int CH = 64;          // cached code steps (covers seq_len 63)
constexpr int WPB = 16;         // walks per block
constexpr int BMW = 626;        // bitmap words per walk
constexpr int NMAX = BMW * 32;  // 20,032 rows max for fast path
constexpr int SEQS = 66;        // seqL stride (u16)
constexpr int KSTRIDE = 65;     // fallback keys stride
constexpr int VISW = 2048;      // fallback bitmap words (N <= 65536)

// =================== FAST kernel: fused, ws-free ==========================
__global__ __launch_bounds__(256) void walk_fast(
    const float* __restrict__ xyz, const int* __restrict__ nbrs,
    const int* __restrict__ centers, const int* __restrict__ n_faces_p,
    const int* __restrict__ seq_len_p, float* __restrict__ out,
    int s0, int num_walks, int Lp1) {
  __shared__ uint32_t nb01L[NMAX];       // 80,128 B   n0 | n1<<16
  __shared__ uint16_t nb2L[NMAX];        // 40,064 B   n2
  __shared__ uint32_t visL[WPB * BMW];   // 40,064 B   bitmaps / keys scratch
  __shared__ uint16_t seqL[WPB * SEQS];  //  2,112 B
  __shared__ uint8_t  codesL[WPB * CH];  //  1,024 B   -> total 163,392 B

  const int tid = threadIdx.x, lane = tid & 63;
  const int w0 = blockIdx.x * WPB;
  if (w0 >= num_walks) return;
  const int N = *n_faces_p, L = *seq_len_p;
  const int B = s0 / (3 * N), G = num_walks / B;
  const bool fast = (N <= NMAX) && (L <= 63) && (G % WPB == 0);
  if (!fast) return;                      // fallback kernel handles it

  const int b = w0 / G;                   // uniform batch (G%16==0)
  const int* __restrict__ nbs  = nbrs + (size_t)b * N * 3;
  const float* __restrict__ xb = xyz + (size_t)b * N * 3;

  // ---- Phase A: chains (wave0 lanes 0-15) || table staging (tid 64-255) --
  if (tid < 64) {
    if (lane < WPB && (w0 + lane) < num_walks) {
      uint32_t ka, kb;
      tf2x32(0u, 42u, 0u, (uint32_t)(w0 + lane), ka, kb);   // k_0
      visL[(lane * CH + 0) * 2 + 0] = ka;
      visL[(lane * CH + 0) * 2 + 1] = kb;
#pragma clang loop unroll(disable)
      for (int c = 1; c < CH; ++c) {
        tf2x32(ka, kb, 0u, 0u, ka, kb);
        visL[(lane * CH + c) * 2 + 0] = ka;
        visL[(lane * CH + c) * 2 + 1] = kb;
      }
    }
  } else {
    for (int r = tid - 64; r < N; r += 192) {
      const int3 v = *reinterpret_cast<const int3*>(nbs + 3 * (size_t)r);
      nb01L[r] = (uint32_t)v.x | ((uint32_t)v.y << 16);
      nb2L[r]  = (uint16_t)v.z;
    }
  }
  __syncthreads();

  // ---- Phase B: 4 randint trees per thread (1024 = 16 walks x 64 steps) --
  for (int t = 0; t < 4; ++t) {
    const int g = tid * 4 + t;
    const int wl = g >> 6;
    if ((w0 + wl) < num_walks) {
      const uint32_t ka = visL[g * 2 + 0], kb = visL[g * 2 + 1];
      uint32_t k1a, k1b, hi, lo;
      tf2x32(ka, kb, 0u, 1u, k1a, k1b);   // k1 = split(k,4)[1]
      randbits(k1a, k1b, hi, lo);
      codesL[g] = (uint8_t)pick_code(hi, lo);
    }
  }
  __syncthreads();

  // ---- Phase C: zero bitmaps, then wave0 SIMT-walks 16 walks -------------
  for (int j = tid; j < WPB * BMW; j += 256) visL[j] = 0u;
  __syncthreads();

  if (tid < 64) {
    const int wl = lane;                  // walk-in-block
    const int wg = w0 + wl;
    const bool alive = (wl < WPB) && (wg < num_walks);

    int f0 = 0, n0 = 0, n1 = 0, n2 = 0, i = 1, bs = 1, cstep = 0;
    if (alive) {
      f0 = centers[wg];
      seqL[wl * SEQS + 0] = (uint16_t)f0;
      visL[wl * BMW + ((unsigned)f0 >> 5)] = 1u << (f0 & 31);
      const uint32_t p = nb01L[f0];
      n0 = (int)(p & 0xffffu); n1 = (int)(p >> 16); n2 = (int)nb2L[f0];
    }
    for (;;) {
      const bool go = alive && (i <= L);
      if (!__ballot(go)) break;
      if (go) {
        const int idx = cstep; ++cstep;
        const uint32_t wa = visL[wl * BMW + ((unsigned)n0 >> 5)];
        const uint32_t wb = visL[wl * BMW + ((unsigned)n1 >> 5)];
        const uint32_t wc = visL[wl * BMW + ((unsigned)n2 >> 5)];
        const uint32_t pA = nb01L[n0]; const uint32_t a2 = nb2L[n0];
        const uint32_t pB = nb01L[n1]; const uint32_t b2 = nb2L[n1];
        const uint32_t pC = nb01L[n2]; const uint32_t c2 = nb2L[n2];
        const uint32_t u0 = ((wa >> (n0 & 31)) & 1u) ^ 1u;
        const uint32_t u1 = ((wb >> (n1 & 31)) & 1u) ^ 1u;
        const uint32_t u2 = ((wc >> (n2 & 31)) & 1u) ^ 1u;
        const uint32_t cnt = u0 + u1 + u2;

        int to_add, sel;
        if (__builtin_expect(cnt == 0, 0)) {
          // ---- rare backtrack (per-lane, live hashing, bit-exact) ----
          sel = -1;
          uint32_t kia, kib;
          live_key(wg, idx, kia, kib);
          uint32_t kka, kkb;
          tf2x32(kia, kib, 0u, 2u, kka, kkb);  // k2
          bool found = false;
          int ta = 0, bsc = bs;
          while (!found && i > bsc) {
            uint32_t ca, cb, kpa, kpb;
            tf2x32(kka, kkb, 0u, 0u, ca, cb);
            tf2x32(kka, kkb, 0u, 1u, kpa, kpb);
            const int back = (int)seqL[wl * SEQS + (i - bsc - 1)];
            const uint32_t pm = nb01L[back];
            const int m0 = (int)(pm & 0xffffu), m1 = (int)(pm >> 16);
            const int m2 = (int)nb2L[back];
            const uint32_t e0 =
                ((visL[wl * BMW + (m0 >> 5)] >> (m0 & 31)) & 1u) ^ 1u;
            const uint32_t e1 =
                ((visL[wl * BMW + (m1 >> 5)] >> (m1 & 31)) & 1u) ^ 1u;
            const uint32_t e2 =
                ((visL[wl * BMW + (m2 >> 5)] >> (m2 & 31)) & 1u) ^ 1u;
            const uint32_t bc = e0 + e1 + e2;
            if (bc > 0) {
              uint32_t bhi, blo;
              randbits(kpa, kpb, bhi, blo);
              const uint32_t bcode = pick_code(bhi, blo);
              const uint32_t r3 = bcode & 3u, r2 = (bcode >> 2) & 1u;
              const uint32_t t2v = (bc == 3 ? r3 : (bc == 2 ? r2 : 0)) + 1;
              ta = (e0 == t2v) ? m0 : ((e0 + e1 == t2v) ? m1 : m2);
              found = true;
            } else {
              bsc += 2;
            }
            kka = ca; kkb = cb;
          }
          if (found) {
            const int i_new = i - bsc;
            for (int a = i_new; a < i; ++a)
              seqL[wl * SEQS + a] = (uint16_t)ta;   // ref's seq-splat
            to_add = ta; bs = bsc; i = i_new;
          } else {
            uint32_t k3a, k3b, rh, rl;
            tf2x32(kia, kib, 0u, 3u, k3a, k3b);     // k3
            randbits(k3a, k3b, rh, rl);
            to_add = (int)r_generic(rh, rl, (uint32_t)N);
            bs = 1;
          }
        } else {
          // ---- common path ----
          uint32_t code;
          if (__builtin_expect(idx >= CH, 0)) {     // beyond cached steps
            uint32_t ia, ib, k1a, k1b, h2, l2;
            live_key(wg, idx, ia, ib);
            tf2x32(ia, ib, 0u, 1u, k1a, k1b);
            randbits(k1a, k1b, h2, l2);
            code = pick_code(h2, l2);
          } else {
            code = codesL[(wl << 6) | idx];
          }
          const uint32_t r3 = code & 3u, r2 = (code >> 2) & 1u;
          const uint32_t target = (cnt == 3 ? r3 : (cnt == 2 ? r2 : 0)) + 1;
          sel = (u0 == target) ? 0 : ((u0 + u1 == target) ? 1 : 2);
          to_add = (sel == 0) ? n0 : ((sel == 1) ? n1 : n2);
          bs = 1;
        }
        // ---- common tail ----
        const unsigned word = wl * BMW + ((unsigned)to_add >> 5);
        visL[word] = visL[word] | (1u << (to_add & 31));
        seqL[wl * SEQS + i] = (uint16_t)to_add;
        ++i;
        if (sel == 0)      { n0 = (int)(pA & 0xffffu); n1 = (int)(pA >> 16); n2 = (int)a2; }
        else if (sel == 1) { n0 = (int)(pB & 0xffffu); n1 = (int)(pB >> 16); n2 = (int)b2; }
        else if (sel == 2) { n0 = (int)(pC & 0xffffu); n1 = (int)(pC >> 16); n2 = (int)c2; }
        else {
          const uint32_t p = nb01L[to_add];
          n0 = (int)(p & 0xffffu); n1 = (int)(p >> 16); n2 = (int)nb2L[to_add];
        }
      }
    }
  }
  __syncthreads();

  // ---- Phase D: gather + recenter straight from seqL ---------------------
  for (int idx = tid; idx < WPB * Lp1; idx += 256) {
    const int wl = idx / Lp1, t = idx - wl * Lp1;
    const int wg = w0 + wl;
    if (wg < num_walks) {
      const int node = (int)seqL[wl * SEQS + t];
      const int c0 = centers[wg];
      float3 v;
      v.x = xb[3 * (size_t)node + 0] - xb[3 * (size_t)c0 + 0];
      v.y = xb[3 * (size_t)node + 1] - xb[3 * (size_t)c0 + 1];
      v.z = xb[3 * (size_t)node + 2] - xb[3 * (size_t)c0 + 2];
      *reinterpret_cast<float3*>(out + ((size_t)wg * Lp1 + t) * 3) = v;
    }
  }
}

// ============ FALLBACK kernel: any shape (R10-verified), ws-free ==========
__global__ __launch_bounds__(1024) void walk_any(
    const float* __restrict__ xyz, const int* __restrict__ nbrs,
    const int* __restrict__ centers, const int* __restrict__ n_faces_p,
    const int* __restrict__ seq_len_p, float* __restrict__ out,
    int s0, int num_walks, int Lp1) {
  __shared__ uint32_t visL[WPB * VISW];
  __shared__ uint2 keysL[WPB * KSTRIDE];

  const int tid = threadIdx.x;
  const int wv = tid >> 6, lane = tid & 63;
  const int w0 = blockIdx.x * WPB;
  if (w0 >= num_walks) return;
  const int N = *n_faces_p, L = *seq_len_p;
  const int B = s0 / (3 * N), G = num_walks / B;
  if ((N <= NMAX) && (L <= 63) && (G % WPB == 0)) return;  // fast handled it
  const int w = w0 + wv;
  const bool active = (w < num_walks);
  const bool bm_ok = (N <= VISW * 32);

  const int bb = (active ? w : w0) / G;
  const int* __restrict__ nb   = nbrs + (size_t)bb * N * 3;
  const float* __restrict__ xb = xyz + (size_t)bb * N * 3;

  const int f0 = active ? centers[w] : 0;
  int3 row = active ? *reinterpret_cast<const int3*>(nb + 3 * (size_t)f0)
                    : make_int3(0, 0, 0);

  uint32_t* __restrict__ visW = visL + wv * VISW;
  if (bm_ok) {
    for (int j = lane; j < VISW; j += 64) visW[j] = 0u;
    if (lane == 0 && active) visW[(unsigned)f0 >> 5] = 1u << (f0 & 31);
  }
  if (wv == 0 && lane < WPB && (w0 + lane) < num_walks) {
    uint32_t ka, kb;
    tf2x32(0u, 42u, 0u, (uint32_t)(w0 + lane), ka, kb);
    keysL[lane * KSTRIDE + 0] = make_uint2(ka, kb);
#pragma clang loop unroll(disable)
    for (int c2 = 1; c2 < CH; ++c2) {
      tf2x32(ka, kb, 0u, 0u, ka, kb);
      keysL[lane * KSTRIDE + c2] = make_uint2(ka, kb);
    }
  }
  __syncthreads();
  if (!active) return;

  const uint2 mykey = keysL[wv * KSTRIDE + lane];
  uint32_t mycode;
  {
    uint32_t k1a, k1b, hi, lo;
    tf2x32(mykey.x, mykey.y, 0u, 1u, k1a, k1b);
    randbits(k1a, k1b, hi, lo);
    mycode = pick_code(hi, lo);
  }
  uint32_t extka = 0, extkb = 0;
  int extc = -1;
  auto get_key = [&](int idx, uint32_t& ra, uint32_t& rb) {
    if (idx < CH) {
      ra = (uint32_t)__shfl((int)mykey.x, idx);
      rb = (uint32_t)__shfl((int)mykey.y, idx);
    } else {
      if (extc < 0) {
        extka = (uint32_t)__shfl((int)mykey.x, CH - 1);
        extkb = (uint32_t)__shfl((int)mykey.y, CH - 1);
        extc = CH - 1;
      }
      while (extc < idx) { tf2x32(extka, extkb, 0u, 0u, extka, extkb); ++extc; }
      ra = extka; rb = extkb;
    }
  };

  int seqr = (lane == 0) ? f0 : -1;
  int i = 1, bs = 1, c = 0;
  int hist = (lane == 0) ? f0 : -1, hist2 = -1;

  while (i <= L) {
    const int idx = c; ++c;
    const bool deep = (idx >= CH);
    const int n0 = row.x, n1 = row.y, n2 = row.z;
    uint32_t u0, u1, u2;
    if (bm_ok) {
      u0 = ((visW[(unsigned)n0 >> 5] >> (n0 & 31)) & 1u) ^ 1u;
      u1 = ((visW[(unsigned)n1 >> 5] >> (n1 & 31)) & 1u) ^ 1u;
      u2 = ((visW[(unsigned)n2 >> 5] >> (n2 & 31)) & 1u) ^ 1u;
    } else {
      int v0 = __any(hist == n0), v1 = __any(hist == n1), v2 = __any(hist == n2);
      if (deep) {
        v0 |= __any(hist2 == n0); v1 |= __any(hist2 == n1); v2 |= __any(hist2 == n2);
      }
      u0 = 1 - v0; u1 = 1 - v1; u2 = 1 - v2;
    }
    const uint32_t cnt = u0 + u1 + u2;

    int to_add;
    bool hit = false;
    int bsf = bs;
    if (cnt > 0) {
      uint32_t code;
      if (deep) {
        uint32_t ia, ib, k1a, k1b, hi, lo;
        get_key(idx, ia, ib);
        tf2x32(ia, ib, 0u, 1u, k1a, k1b);
        randbits(k1a, k1b, hi, lo);
        code = pick_code(hi, lo);
      } else {
        code = (uint32_t)__builtin_amdgcn_readlane((int)mycode, idx);
      }
      const uint32_t r3 = code & 3u, r2 = (code >> 2) & 1u;
      const uint32_t target = (cnt == 3 ? r3 : (cnt == 2 ? r2 : 0)) + 1;
      to_add = (u0 == target) ? n0 : ((u0 + u1 == target) ? n1 : n2);
    } else {
      uint32_t kia, kib;
      get_key(idx, kia, kib);
      uint32_t kka, kkb;
      tf2x32(kia, kib, 0u, 2u, kka, kkb);
      bool found = false;
      int ta = 0, bsc = bs;
      while (!found && i > bsc) {
        uint32_t ca, cb, kpa, kpb;
        tf2x32(kka, kkb, 0u, 0u, ca, cb);
        tf2x32(kka, kkb, 0u, 1u, kpa, kpb);
        const int back = __shfl(seqr, i - bsc - 1);
        const int3 br = *reinterpret_cast<const int3*>(nb + 3 * (size_t)back);
        uint32_t e0, e1, e2;
        if (bm_ok) {
          e0 = ((visW[(unsigned)br.x >> 5] >> (br.x & 31)) & 1u) ^ 1u;
          e1 = ((visW[(unsigned)br.y >> 5] >> (br.y & 31)) & 1u) ^ 1u;
          e2 = ((visW[(unsigned)br.z >> 5] >> (br.z & 31)) & 1u) ^ 1u;
        } else {
          int a0 = __any(hist == br.x), a1 = __any(hist == br.y), a2m = __any(hist == br.z);
          if (deep) {
            a0 |= __any(hist2 == br.x); a1 |= __any(hist2 == br.y); a2m |= __any(hist2 == br.z);
          }
          e0 = 1 - a0; e1 = 1 - a1; e2 = 1 - a2m;
        }
        const uint32_t bc = e0 + e1 + e2;
        if (bc > 0) {
          uint32_t bhi, blo;
          randbits(kpa, kpb, bhi, blo);
          const uint32_t bcode = pick_code(bhi, blo);
          const uint32_t r3 = bcode & 3u, r2 = (bcode >> 2) & 1u;
          const uint32_t t2v = (bc == 3 ? r3 : (bc == 2 ? r2 : 0)) + 1;
          ta = (e0 == t2v) ? br.x : ((e0 + e1 == t2v) ? br.y : br.z);
          found = true;
        } else {
          bsc += 2;
        }
        kka = ca; kkb = cb;
      }
      if (found) {
        to_add = ta; hit = true; bsf = bsc;
      } else {
        uint32_t k3a, k3b, rh, rl;
        tf2x32(kia, kib, 0u, 3u, k3a, k3b);
        randbits(k3a, k3b, rh, rl);
        to_add = (int)r_generic(rh, rl, (uint32_t)N);
      }
    }

    int i_new, up;
    if (hit) { i_new = i - bsf; bs = bsf; up = i - 1; }
    else     { i_new = i;       bs = 1;   up = i; }
    seqr = (lane >= i_new && lane <= up) ? to_add : seqr;
    if (bm_ok) {
      if (lane == 0) {
        const unsigned word = (unsigned)to_add >> 5;
        visW[word] |= 1u << (to_add & 31);
      }
    } else {
      const int slot = idx + 1;
      if (slot < CH)          hist  = (lane == slot)      ? to_add : hist;
      else if (slot < 2 * CH) hist2 = (lane == slot - CH) ? to_add : hist2;
    }
    i = i_new + 1;
    row = *reinterpret_cast<const int3*>(nb + 3 * (size_t)to_add);
  }

  const float cx = xb[3 * (size_t)f0 + 0];
  const float cy = xb[3 * (size_t)f0 + 1];
  const float cz = xb[3 * (size_t)f0 + 2];
  if (lane < Lp1) {
    const int node = seqr;
    float3 v;
    v.x = xb[3 * (size_t)node + 0] - cx;
    v.y = xb[3 * (size_t)node + 1] - cy;
    v.z = xb[3 * (size_t)node + 2] - cz;
    *reinterpret_cast<float3*>(out + ((size_t)w * Lp1 + lane) * 3) = v;
  }
}

}  // namespace

extern "C" void kernel_launch(void* const* d_in, const int* in_sizes, int n_in,
                              void* d_out, int out_size, void* d_ws, size_t ws_size,
                              hipStream_t stream) {
  const float* xyz     = (const float*)d_in[0];
  const int*   nbrs    = (const int*)d_in[1];
  const int*   centers = (const int*)d_in[2];
  const int*   n_faces = (const int*)d_in[3];
  const int*   seq_len = (const int*)d_in[4];
  float* out = (float*)d_out;

  const int s0 = in_sizes[0];                  // B*N*3
  const int num_walks = in_sizes[2];           // B*G
  const int Lp1 = out_size / (3 * num_walks);  // seq_len+1

  const int blocks = (num_walks + WPB - 1) / WPB;
  // Exactly one of these does the work (grid-uniform shape test); the other
  // exits in ~2us. No d_ws use anywhere (avoids the 40us poison-fill tax).
  walk_fast<<<blocks, 256, 0, stream>>>(
      xyz, nbrs, centers, n_faces, seq_len, out, s0, num_walks, Lp1);
  walk_any<<<blocks, WPB * 64, 0, stream>>>(
      xyz, nbrs, centers, n_faces, seq_len, out, s0, num_walks, Lp1);
}

// Round 13
// 100.449 us; speedup vs baseline: 1.1273x; 1.0337x over previous
//
#include <hip/hip_runtime.h>
#include <stdint.h>
#include <stddef.h>

// MambaMesh random-walk + gather-recenter.  R13: fix staging throughput.
// PRNG (bit-exact vs JAX partitionable Threefry, verified R1-R12, absmax 0.0):
//   split(key,n)[j]        = threefry2x32(key; 0, j)   (both output words)
//   random_bits(key,32,()) = xor-fold of threefry2x32(key; 0, 0)
// R12 lesson (VALUBusy 12%): 192 staging threads x 104 serial load->wait->
// ds_write iterations ~= 20us of unpipelined stalls. R13: 512-thread block,
// 448 stagers, manual unroll x4 with batched independent loads (one vmcnt
// group per 4 rows) -> staging ~3us, hidden under the ~8us chain phase.
// Everything else is the verified R12 structure: fused ws-free SIMT walk
// (wave0 lanes0-15 = 16 walks), LDS nb table + bitmaps, in-LDS gather.

namespace {

__device__ __forceinline__ uint32_t rotl32(uint32_t x, int r) {
  return (x << r) | (x >> (32 - r));
}

// Threefry-2x32, 20 rounds — exactly JAX's threefry2x32_p.
__device__ __forceinline__ void tf2x32(uint32_t ka, uint32_t kb,
                                       uint32_t x0, uint32_t x1,
                                       uint32_t& o0, uint32_t& o1) {
  const uint32_t kc = ka ^ kb ^ 0x1BD11BDAu;
  x0 += ka; x1 += kb;
#define TF_R4(r0, r1, r2, r3)                          \
  x0 += x1; x1 = rotl32(x1, r0); x1 ^= x0;             \
  x0 += x1; x1 = rotl32(x1, r1); x1 ^= x0;             \
  x0 += x1; x1 = rotl32(x1, r2); x1 ^= x0;             \
  x0 += x1; x1 = rotl32(x1, r3); x1 ^= x0;
  TF_R4(13, 15, 26, 6)  x0 += kb; x1 += kc + 1u;
  TF_R4(17, 29, 16, 24) x0 += kc; x1 += ka + 2u;
  TF_R4(13, 15, 26, 6)  x0 += ka; x1 += kb + 3u;
  TF_R4(17, 29, 16, 24) x0 += kb; x1 += kc + 4u;
  TF_R4(13, 15, 26, 6)  x0 += kc; x1 += ka + 5u;
#undef TF_R4
  o0 = x0; o1 = x1;
}

__device__ __forceinline__ void randbits(uint32_t ka, uint32_t kb,
                                         uint32_t& hi, uint32_t& lo) {
  uint32_t s0a, s0b, s1a, s1b, h0, h1;
  tf2x32(ka, kb, 0u, 0u, s0a, s0b);
  tf2x32(ka, kb, 0u, 1u, s1a, s1b);
  tf2x32(s0a, s0b, 0u, 0u, h0, h1);
  hi = h0 ^ h1;
  tf2x32(s1a, s1b, 0u, 0u, h0, h1);
  lo = h0 ^ h1;
}

__device__ __forceinline__ uint32_t r_generic(uint32_t hi, uint32_t lo,
                                              uint32_t span) {
  uint32_t mult = 65536u % span;
  mult = (mult * mult) % span;
  return ((hi % span) * mult + (lo % span)) % span;
}

// pick code: r3 (span=3 result) in bits 0..1, r2 (span=2 result) in bit 2.
__device__ __forceinline__ uint32_t pick_code(uint32_t hi, uint32_t lo) {
  return ((hi % 3u + lo % 3u) % 3u) | ((lo & 1u) << 2);
}

// k_idx recomputed from k0 — RARE paths only (bit-exact).
__device__ __noinline__ void live_key(int w, int idx, uint32_t& ka,
                                      uint32_t& kb) {
  tf2x32(0u, 42u, 0u, (uint32_t)w, ka, kb);
  for (int c = 0; c < idx; ++c) tf2x32(ka, kb, 0u, 0u, ka, kb);
}

constexpr int CH = 64;          // cached code steps (covers seq_len 63)
constexpr int WPB = 16;         // walks per block
constexpr int BMW = 626;        // bitmap words per walk
constexpr int NMAX = BMW * 32;  // 20,032 rows max for fast path
constexpr int SEQS = 66;        // seqL stride (u16)
constexpr int KSTRIDE = 65;     // fallback keys stride
constexpr int VISW = 2048;      // fallback bitmap words (N <= 65536)
constexpr int NTHR = 512;       // fast-kernel block size
constexpr int NSTG = NTHR - 64; // staging threads (448)

// =================== FAST kernel: fused, ws-free ==========================
__global__ __launch_bounds__(NTHR) void walk_fast(
    const float* __restrict__ xyz, const int* __restrict__ nbrs,
    const int* __restrict__ centers, const int* __restrict__ n_faces_p,
    const int* __restrict__ seq_len_p, float* __restrict__ out,
    int s0, int num_walks, int Lp1) {
  __shared__ uint32_t nb01L[NMAX];       // 80,128 B   n0 | n1<<16
  __shared__ uint16_t nb2L[NMAX];        // 40,064 B   n2
  __shared__ uint32_t visL[WPB * BMW];   // 40,064 B   bitmaps / keys scratch
  __shared__ uint16_t seqL[WPB * SEQS];  //  2,112 B
  __shared__ uint8_t  codesL[WPB * CH];  //  1,024 B   -> total 163,392 B

  const int tid = threadIdx.x, lane = tid & 63;
  const int w0 = blockIdx.x * WPB;
  if (w0 >= num_walks) return;
  const int N = *n_faces_p, L = *seq_len_p;
  const int B = s0 / (3 * N), G = num_walks / B;
  const bool fast = (N <= NMAX) && (L <= 63) && (G % WPB == 0);
  if (!fast) return;                      // fallback kernel handles it

  const int b = w0 / G;                   // uniform batch (G%16==0)
  const int* __restrict__ nbs  = nbrs + (size_t)b * N * 3;
  const float* __restrict__ xb = xyz + (size_t)b * N * 3;

  // ---- Phase A: chains (wave0 lanes 0-15) || staging (tid 64..511) -------
  if (tid < 64) {
    if (lane < WPB && (w0 + lane) < num_walks) {
      uint32_t ka, kb;
      tf2x32(0u, 42u, 0u, (uint32_t)(w0 + lane), ka, kb);   // k_0
      visL[(lane * CH + 0) * 2 + 0] = ka;
      visL[(lane * CH + 0) * 2 + 1] = kb;
#pragma clang loop unroll(disable)
      for (int c = 1; c < CH; ++c) {
        tf2x32(ka, kb, 0u, 0u, ka, kb);
        visL[(lane * CH + c) * 2 + 0] = ka;
        visL[(lane * CH + c) * 2 + 1] = kb;
      }
    }
  } else {
    // 448 stagers, unroll x4: 4 independent loads in flight per wait group.
    int r = tid - 64;
    for (; r + 3 * NSTG < N; r += 4 * NSTG) {
      const int3 v0 = *reinterpret_cast<const int3*>(nbs + 3 * (size_t)r);
      const int3 v1 = *reinterpret_cast<const int3*>(nbs + 3 * (size_t)(r + NSTG));
      const int3 v2 = *reinterpret_cast<const int3*>(nbs + 3 * (size_t)(r + 2 * NSTG));
      const int3 v3 = *reinterpret_cast<const int3*>(nbs + 3 * (size_t)(r + 3 * NSTG));
      nb01L[r]            = (uint32_t)v0.x | ((uint32_t)v0.y << 16);
      nb2L[r]             = (uint16_t)v0.z;
      nb01L[r + NSTG]     = (uint32_t)v1.x | ((uint32_t)v1.y << 16);
      nb2L[r + NSTG]      = (uint16_t)v1.z;
      nb01L[r + 2 * NSTG] = (uint32_t)v2.x | ((uint32_t)v2.y << 16);
      nb2L[r + 2 * NSTG]  = (uint16_t)v2.z;
      nb01L[r + 3 * NSTG] = (uint32_t)v3.x | ((uint32_t)v3.y << 16);
      nb2L[r + 3 * NSTG]  = (uint16_t)v3.z;
    }
    for (; r < N; r += NSTG) {
      const int3 v = *reinterpret_cast<const int3*>(nbs + 3 * (size_t)r);
      nb01L[r] = (uint32_t)v.x | ((uint32_t)v.y << 16);
      nb2L[r]  = (uint16_t)v.z;
    }
  }
  __syncthreads();

  // ---- Phase B: 2 randint trees per thread (1024 = 16 walks x 64 steps) --
  for (int t = 0; t < 2; ++t) {
    const int g = tid * 2 + t;
    const int wl = g >> 6;
    if ((w0 + wl) < num_walks) {
      const uint32_t ka = visL[g * 2 + 0], kb = visL[g * 2 + 1];
      uint32_t k1a, k1b, hi, lo;
      tf2x32(ka, kb, 0u, 1u, k1a, k1b);   // k1 = split(k,4)[1]
      randbits(k1a, k1b, hi, lo);
      codesL[g] = (uint8_t)pick_code(hi, lo);
    }
  }
  __syncthreads();

  // ---- Phase C: zero bitmaps, then wave0 SIMT-walks 16 walks -------------
  for (int j = tid; j < WPB * BMW; j += NTHR) visL[j] = 0u;
  __syncthreads();

  if (tid < 64) {
    const int wl = lane;                  // walk-in-block
    const int wg = w0 + wl;
    const bool alive = (wl < WPB) && (wg < num_walks);

    int f0 = 0, n0 = 0, n1 = 0, n2 = 0, i = 1, bs = 1, cstep = 0;
    if (alive) {
      f0 = centers[wg];
      seqL[wl * SEQS + 0] = (uint16_t)f0;
      visL[wl * BMW + ((unsigned)f0 >> 5)] = 1u << (f0 & 31);
      const uint32_t p = nb01L[f0];
      n0 = (int)(p & 0xffffu); n1 = (int)(p >> 16); n2 = (int)nb2L[f0];
    }
    for (;;) {
      const bool go = alive && (i <= L);
      if (!__ballot(go)) break;
      if (go) {
        const int idx = cstep; ++cstep;
        const uint32_t wa = visL[wl * BMW + ((unsigned)n0 >> 5)];
        const uint32_t wb = visL[wl * BMW + ((unsigned)n1 >> 5)];
        const uint32_t wc = visL[wl * BMW + ((unsigned)n2 >> 5)];
        const uint32_t pA = nb01L[n0]; const uint32_t a2 = nb2L[n0];
        const uint32_t pB = nb01L[n1]; const uint32_t b2 = nb2L[n1];
        const uint32_t pC = nb01L[n2]; const uint32_t c2 = nb2L[n2];
        const uint32_t u0 = ((wa >> (n0 & 31)) & 1u) ^ 1u;
        const uint32_t u1 = ((wb >> (n1 & 31)) & 1u) ^ 1u;
        const uint32_t u2 = ((wc >> (n2 & 31)) & 1u) ^ 1u;
        const uint32_t cnt = u0 + u1 + u2;

        int to_add, sel;
        if (__builtin_expect(cnt == 0, 0)) {
          // ---- rare backtrack (per-lane, live hashing, bit-exact) ----
          sel = -1;
          uint32_t kia, kib;
          live_key(wg, idx, kia, kib);
          uint32_t kka, kkb;
          tf2x32(kia, kib, 0u, 2u, kka, kkb);  // k2
          bool found = false;
          int ta = 0, bsc = bs;
          while (!found && i > bsc) {
            uint32_t ca, cb, kpa, kpb;
            tf2x32(kka, kkb, 0u, 0u, ca, cb);
            tf2x32(kka, kkb, 0u, 1u, kpa, kpb);
            const int back = (int)seqL[wl * SEQS + (i - bsc - 1)];
            const uint32_t pm = nb01L[back];
            const int m0 = (int)(pm & 0xffffu), m1 = (int)(pm >> 16);
            const int m2 = (int)nb2L[back];
            const uint32_t e0 =
                ((visL[wl * BMW + (m0 >> 5)] >> (m0 & 31)) & 1u) ^ 1u;
            const uint32_t e1 =
                ((visL[wl * BMW + (m1 >> 5)] >> (m1 & 31)) & 1u) ^ 1u;
            const uint32_t e2 =
                ((visL[wl * BMW + (m2 >> 5)] >> (m2 & 31)) & 1u) ^ 1u;
            const uint32_t bc = e0 + e1 + e2;
            if (bc > 0) {
              uint32_t bhi, blo;
              randbits(kpa, kpb, bhi, blo);
              const uint32_t bcode = pick_code(bhi, blo);
              const uint32_t r3 = bcode & 3u, r2 = (bcode >> 2) & 1u;
              const uint32_t t2v = (bc == 3 ? r3 : (bc == 2 ? r2 : 0)) + 1;
              ta = (e0 == t2v) ? m0 : ((e0 + e1 == t2v) ? m1 : m2);
              found = true;
            } else {
              bsc += 2;
            }
            kka = ca; kkb = cb;
          }
          if (found) {
            const int i_new = i - bsc;
            for (int a = i_new; a < i; ++a)
              seqL[wl * SEQS + a] = (uint16_t)ta;   // ref's seq-splat
            to_add = ta; bs = bsc; i = i_new;
          } else {
            uint32_t k3a, k3b, rh, rl;
            tf2x32(kia, kib, 0u, 3u, k3a, k3b);     // k3
            randbits(k3a, k3b, rh, rl);
            to_add = (int)r_generic(rh, rl, (uint32_t)N);
            bs = 1;
          }
        } else {
          // ---- common path ----
          uint32_t code;
          if (__builtin_expect(idx >= CH, 0)) {     // beyond cached steps
            uint32_t ia, ib, k1a, k1b, h2, l2;
            live_key(wg, idx, ia, ib);
            tf2x32(ia, ib, 0u, 1u, k1a, k1b);
            randbits(k1a, k1b, h2, l2);
            code = pick_code(h2, l2);
          } else {
            code = codesL[(wl << 6) | idx];
          }
          const uint32_t r3 = code & 3u, r2 = (code >> 2) & 1u;
          const uint32_t target = (cnt == 3 ? r3 : (cnt == 2 ? r2 : 0)) + 1;
          sel = (u0 == target) ? 0 : ((u0 + u1 == target) ? 1 : 2);
          to_add = (sel == 0) ? n0 : ((sel == 1) ? n1 : n2);
          bs = 1;
        }
        // ---- common tail ----
        const unsigned word = wl * BMW + ((unsigned)to_add >> 5);
        visL[word] = visL[word] | (1u << (to_add & 31));
        seqL[wl * SEQS + i] = (uint16_t)to_add;
        ++i;
        if (sel == 0)      { n0 = (int)(pA & 0xffffu); n1 = (int)(pA >> 16); n2 = (int)a2; }
        else if (sel == 1) { n0 = (int)(pB & 0xffffu); n1 = (int)(pB >> 16); n2 = (int)b2; }
        else if (sel == 2) { n0 = (int)(pC & 0xffffu); n1 = (int)(pC >> 16); n2 = (int)c2; }
        else {
          const uint32_t p = nb01L[to_add];
          n0 = (int)(p & 0xffffu); n1 = (int)(p >> 16); n2 = (int)nb2L[to_add];
        }
      }
    }
  }
  __syncthreads();

  // ---- Phase D: gather + recenter straight from seqL ---------------------
  for (int idx = tid; idx < WPB * Lp1; idx += NTHR) {
    const int wl = idx / Lp1, t = idx - wl * Lp1;
    const int wg = w0 + wl;
    if (wg < num_walks) {
      const int node = (int)seqL[wl * SEQS + t];
      const int c0 = centers[wg];
      float3 v;
      v.x = xb[3 * (size_t)node + 0] - xb[3 * (size_t)c0 + 0];
      v.y = xb[3 * (size_t)node + 1] - xb[3 * (size_t)c0 + 1];
      v.z = xb[3 * (size_t)node + 2] - xb[3 * (size_t)c0 + 2];
      *reinterpret_cast<float3*>(out + ((size_t)wg * Lp1 + t) * 3) = v;
    }
  }
}

// ============ FALLBACK kernel: any shape (R10-verified), ws-free ==========
__global__ __launch_bounds__(1024) void walk_any(
    const float* __restrict__ xyz, const int* __restrict__ nbrs,
    const int* __restrict__ centers, const int* __restrict__ n_faces_p,
    const int* __restrict__ seq_len_p, float* __restrict__ out,
    int s0, int num_walks, int Lp1) {
  __shared__ uint32_t visL[WPB * VISW];
  __shared__ uint2 keysL[WPB * KSTRIDE];

  const int tid = threadIdx.x;
  const int wv = tid >> 6, lane = tid & 63;
  const int w0 = blockIdx.x * WPB;
  if (w0 >= num_walks) return;
  const int N = *n_faces_p, L = *seq_len_p;
  const int B = s0 / (3 * N), G = num_walks / B;
  if ((N <= NMAX) && (L <= 63) && (G % WPB == 0)) return;  // fast handled it
  const int w = w0 + wv;
  const bool active = (w < num_walks);
  const bool bm_ok = (N <= VISW * 32);

  const int bb = (active ? w : w0) / G;
  const int* __restrict__ nb   = nbrs + (size_t)bb * N * 3;
  const float* __restrict__ xb = xyz + (size_t)bb * N * 3;

  const int f0 = active ? centers[w] : 0;
  int3 row = active ? *reinterpret_cast<const int3*>(nb + 3 * (size_t)f0)
                    : make_int3(0, 0, 0);

  uint32_t* __restrict__ visW = visL + wv * VISW;
  if (bm_ok) {
    for (int j = lane; j < VISW; j += 64) visW[j] = 0u;
    if (lane == 0 && active) visW[(unsigned)f0 >> 5] = 1u << (f0 & 31);
  }
  if (wv == 0 && lane < WPB && (w0 + lane) < num_walks) {
    uint32_t ka, kb;
    tf2x32(0u, 42u, 0u, (uint32_t)(w0 + lane), ka, kb);
    keysL[lane * KSTRIDE + 0] = make_uint2(ka, kb);
#pragma clang loop unroll(disable)
    for (int c2 = 1; c2 < CH; ++c2) {
      tf2x32(ka, kb, 0u, 0u, ka, kb);
      keysL[lane * KSTRIDE + c2] = make_uint2(ka, kb);
    }
  }
  __syncthreads();
  if (!active) return;

  const uint2 mykey = keysL[wv * KSTRIDE + lane];
  uint32_t mycode;
  {
    uint32_t k1a, k1b, hi, lo;
    tf2x32(mykey.x, mykey.y, 0u, 1u, k1a, k1b);
    randbits(k1a, k1b, hi, lo);
    mycode = pick_code(hi, lo);
  }
  uint32_t extka = 0, extkb = 0;
  int extc = -1;
  auto get_key = [&](int idx, uint32_t& ra, uint32_t& rb) {
    if (idx < CH) {
      ra = (uint32_t)__shfl((int)mykey.x, idx);
      rb = (uint32_t)__shfl((int)mykey.y, idx);
    } else {
      if (extc < 0) {
        extka = (uint32_t)__shfl((int)mykey.x, CH - 1);
        extkb = (uint32_t)__shfl((int)mykey.y, CH - 1);
        extc = CH - 1;
      }
      while (extc < idx) { tf2x32(extka, extkb, 0u, 0u, extka, extkb); ++extc; }
      ra = extka; rb = extkb;
    }
  };

  int seqr = (lane == 0) ? f0 : -1;
  int i = 1, bs = 1, c = 0;
  int hist = (lane == 0) ? f0 : -1, hist2 = -1;

  while (i <= L) {
    const int idx = c; ++c;
    const bool deep = (idx >= CH);
    const int n0 = row.x, n1 = row.y, n2 = row.z;
    uint32_t u0, u1, u2;
    if (bm_ok) {
      u0 = ((visW[(unsigned)n0 >> 5] >> (n0 & 31)) & 1u) ^ 1u;
      u1 = ((visW[(unsigned)n1 >> 5] >> (n1 & 31)) & 1u) ^ 1u;
      u2 = ((visW[(unsigned)n2 >> 5] >> (n2 & 31)) & 1u) ^ 1u;
    } else {
      int v0 = __any(hist == n0), v1 = __any(hist == n1), v2 = __any(hist == n2);
      if (deep) {
        v0 |= __any(hist2 == n0); v1 |= __any(hist2 == n1); v2 |= __any(hist2 == n2);
      }
      u0 = 1 - v0; u1 = 1 - v1; u2 = 1 - v2;
    }
    const uint32_t cnt = u0 + u1 + u2;

    int to_add;
    bool hit = false;
    int bsf = bs;
    if (cnt > 0) {
      uint32_t code;
      if (deep) {
        uint32_t ia, ib, k1a, k1b, hi, lo;
        get_key(idx, ia, ib);
        tf2x32(ia, ib, 0u, 1u, k1a, k1b);
        randbits(k1a, k1b, hi, lo);
        code = pick_code(hi, lo);
      } else {
        code = (uint32_t)__builtin_amdgcn_readlane((int)mycode, idx);
      }
      const uint32_t r3 = code & 3u, r2 = (code >> 2) & 1u;
      const uint32_t target = (cnt == 3 ? r3 : (cnt == 2 ? r2 : 0)) + 1;
      to_add = (u0 == target) ? n0 : ((u0 + u1 == target) ? n1 : n2);
    } else {
      uint32_t kia, kib;
      get_key(idx, kia, kib);
      uint32_t kka, kkb;
      tf2x32(kia, kib, 0u, 2u, kka, kkb);
      bool found = false;
      int ta = 0, bsc = bs;
      while (!found && i > bsc) {
        uint32_t ca, cb, kpa, kpb;
        tf2x32(kka, kkb, 0u, 0u, ca, cb);
        tf2x32(kka, kkb, 0u, 1u, kpa, kpb);
        const int back = __shfl(seqr, i - bsc - 1);
        const int3 br = *reinterpret_cast<const int3*>(nb + 3 * (size_t)back);
        uint32_t e0, e1, e2;
        if (bm_ok) {
          e0 = ((visW[(unsigned)br.x >> 5] >> (br.x & 31)) & 1u) ^ 1u;
          e1 = ((visW[(unsigned)br.y >> 5] >> (br.y & 31)) & 1u) ^ 1u;
          e2 = ((visW[(unsigned)br.z >> 5] >> (br.z & 31)) & 1u) ^ 1u;
        } else {
          int a0 = __any(hist == br.x), a1 = __any(hist == br.y), a2m = __any(hist == br.z);
          if (deep) {
            a0 |= __any(hist2 == br.x); a1 |= __any(hist2 == br.y); a2m |= __any(hist2 == br.z);
          }
          e0 = 1 - a0; e1 = 1 - a1; e2 = 1 - a2m;
        }
        const uint32_t bc = e0 + e1 + e2;
        if (bc > 0) {
          uint32_t bhi, blo;
          randbits(kpa, kpb, bhi, blo);
          const uint32_t bcode = pick_code(bhi, blo);
          const uint32_t r3 = bcode & 3u, r2 = (bcode >> 2) & 1u;
          const uint32_t t2v = (bc == 3 ? r3 : (bc == 2 ? r2 : 0)) + 1;
          ta = (e0 == t2v) ? br.x : ((e0 + e1 == t2v) ? br.y : br.z);
          found = true;
        } else {
          bsc += 2;
        }
        kka = ca; kkb = cb;
      }
      if (found) {
        to_add = ta; hit = true; bsf = bsc;
      } else {
        uint32_t k3a, k3b, rh, rl;
        tf2x32(kia, kib, 0u, 3u, k3a, k3b);
        randbits(k3a, k3b, rh, rl);
        to_add = (int)r_generic(rh, rl, (uint32_t)N);
      }
    }

    int i_new, up;
    if (hit) { i_new = i - bsf; bs = bsf; up = i - 1; }
    else     { i_new = i;       bs = 1;   up = i; }
    seqr = (lane >= i_new && lane <= up) ? to_add : seqr;
    if (bm_ok) {
      if (lane == 0) {
        const unsigned word = (unsigned)to_add >> 5;
        visW[word] |= 1u << (to_add & 31);
      }
    } else {
      const int slot = idx + 1;
      if (slot < CH)          hist  = (lane == slot)      ? to_add : hist;
      else if (slot < 2 * CH) hist2 = (lane == slot - CH) ? to_add : hist2;
    }
    i = i_new + 1;
    row = *reinterpret_cast<const int3*>(nb + 3 * (size_t)to_add);
  }

  const float cx = xb[3 * (size_t)f0 + 0];
  const float cy = xb[3 * (size_t)f0 + 1];
  const float cz = xb[3 * (size_t)f0 + 2];
  if (lane < Lp1) {
    const int node = seqr;
    float3 v;
    v.x = xb[3 * (size_t)node + 0] - cx;
    v.y = xb[3 * (size_t)node + 1] - cy;
    v.z = xb[3 * (size_t)node + 2] - cz;
    *reinterpret_cast<float3*>(out + ((size_t)w * Lp1 + lane) * 3) = v;
  }
}

}  // namespace

extern "C" void kernel_launch(void* const* d_in, const int* in_sizes, int n_in,
                              void* d_out, int out_size, void* d_ws, size_t ws_size,
                              hipStream_t stream) {
  const float* xyz     = (const float*)d_in[0];
  const int*   nbrs    = (const int*)d_in[1];
  const int*   centers = (const int*)d_in[2];
  const int*   n_faces = (const int*)d_in[3];
  const int*   seq_len = (const int*)d_in[4];
  float* out = (float*)d_out;

  const int s0 = in_sizes[0];                  // B*N*3
  const int num_walks = in_sizes[2];           // B*G
  const int Lp1 = out_size / (3 * num_walks);  // seq_len+1

  const int blocks = (num_walks + WPB - 1) / WPB;
  // Exactly one of these does the work (grid-uniform shape test); the other
  // exits in ~2us. No d_ws use anywhere (avoids the 40us poison-fill tax).
  walk_fast<<<blocks, NTHR, 0, stream>>>(
      xyz, nbrs, centers, n_faces, seq_len, out, s0, num_walks, Lp1);
  walk_any<<<blocks, WPB * 64, 0, stream>>>(
      xyz, nbrs, centers, n_faces, seq_len, out, s0, num_walks, Lp1);
}